// Round 2
// baseline (453.977 us; speedup 1.0000x reference)
//
#include <hip/hip_runtime.h>

#define BTOT 8192
#define SEQ 32
#define IPB 6
#define TPB 128
#define L2E 1.4426950408889634f
#define FSTRIDE 520   // featL row stride (pad so 3 groups/wave hit disjoint banks)
#define VSTRIDE 24    // vbuf row stride

// transpose conv2 weights [c2][ch][ky][kx] -> wt[k][c2], k = ch*25+tap (2400 floats)
__global__ void prep_w2t(const float* __restrict__ w2, float* __restrict__ wt) {
    int idx = blockIdx.x * blockDim.x + threadIdx.x;
    if (idx < 2400) {
        int k = idx >> 4, c2 = idx & 15;
        wt[idx] = w2[c2 * 150 + k];
    }
}

__global__ __launch_bounds__(TPB, 2) void ltc_fused(
    const float* __restrict__ xin,
    const float* __restrict__ w1, const float* __restrict__ b1,
    const float* __restrict__ b2,
    const float* __restrict__ gleak, const float* __restrict__ vleak, const float* __restrict__ cm,
    const float* __restrict__ sigma, const float* __restrict__ mu, const float* __restrict__ ww,
    const float* __restrict__ erev,
    const float* __restrict__ ssigma, const float* __restrict__ smu, const float* __restrict__ sw,
    const float* __restrict__ serev,
    const float* __restrict__ inw, const float* __restrict__ inb,
    const float* __restrict__ outw, const float* __restrict__ outb,
    const float* __restrict__ mask, const float* __restrict__ smask,
    const float* __restrict__ wt,
    float* __restrict__ dout)
{
    // uni: conv scratch (img 1232 + c1p 1440 = 2672 floats) overlaid later by
    // transformed params (665 float4 = 2660 floats)
    __shared__ __align__(16) float uni[2672];
    __shared__ __align__(16) float featL[IPB * FSTRIDE];
    __shared__ __align__(16) float vbuf[IPB * VSTRIDE];

    float* img = uni;            // 28 x 44
    float* c1p = uni + 1232;     // 6 x 12 x 20
    float4* up = (float4*)uni;          // 361 entries {-L2E*sig, L2E*sig*mu, w*erev, w*mask}
    float4* sp = ((float4*)uni) + 361;  // 304 entries

    const int tid = threadIdx.x;
    const int b0 = blockIdx.x * IPB;

    // ---------------- conv phase, one image at a time ----------------
    for (int k = 0; k < IPB; ++k) {
        const int bG = b0 + k;
        const bool valid = bG < BTOT;
        if (valid) {
            for (int idx = tid; idx < 1232; idx += TPB) img[idx] = xin[bG * 1232 + idx];
        }
        __syncthreads();
        if (valid) {
            // conv1: thread = pooled output position, all 6 channels (window reused)
            for (int idx = tid; idx < 240; idx += TPB) {
                int y = idx / 20, xx = idx - (idx / 20) * 20;
                const float* ib = img + (2 * y) * 44 + 2 * xx;
                float win[6][6];
                #pragma unroll
                for (int r = 0; r < 6; ++r) {
                    float2 a = *(const float2*)(ib + r * 44);
                    float2 b = *(const float2*)(ib + r * 44 + 2);
                    float2 c = *(const float2*)(ib + r * 44 + 4);
                    win[r][0] = a.x; win[r][1] = a.y; win[r][2] = b.x;
                    win[r][3] = b.y; win[r][4] = c.x; win[r][5] = c.y;
                }
                for (int ch = 0; ch < 6; ++ch) {
                    const float* wp = w1 + ch * 25;   // uniform -> s_load
                    float a00 = 0.f, a01 = 0.f, a10 = 0.f, a11 = 0.f;
                    #pragma unroll
                    for (int ky = 0; ky < 5; ++ky)
                        #pragma unroll
                        for (int kx = 0; kx < 5; ++kx) {
                            float wv = wp[ky * 5 + kx];
                            a00 = fmaf(wv, win[ky][kx], a00);
                            a01 = fmaf(wv, win[ky][kx + 1], a01);
                            a10 = fmaf(wv, win[ky + 1][kx], a10);
                            a11 = fmaf(wv, win[ky + 1][kx + 1], a11);
                        }
                    float m = fmaxf(fmaxf(a00, a01), fmaxf(a10, a11)) + b1[ch];
                    c1p[ch * 240 + idx] = fmaxf(m, 0.f);
                }
            }
        }
        __syncthreads();
        if (valid) {
            // conv2 as GEMM: thread = pre-pool position (8x16=128), 16 c2 accums,
            // weights via uniform loads from wt (scalar pipe)
            const int oy = tid >> 4, ox = tid & 15;
            float4 A = {0.f,0.f,0.f,0.f}, Bq = {0.f,0.f,0.f,0.f};
            float4 Cq = {0.f,0.f,0.f,0.f}, Dq = {0.f,0.f,0.f,0.f};
            for (int ch = 0; ch < 6; ++ch) {
                const float* rowb = c1p + ch * 240 + oy * 20 + ox;
                const float* wch = wt + (ch * 25 << 4);
                #pragma unroll
                for (int ky = 0; ky < 5; ++ky) {
                    #pragma unroll
                    for (int kx = 0; kx < 5; ++kx) {
                        float xv = rowb[ky * 20 + kx];
                        const float4* wk = (const float4*)(wch + ((ky * 5 + kx) << 4));
                        float4 wa = wk[0], wb = wk[1], wc = wk[2], wd = wk[3];
                        A.x  = fmaf(wa.x, xv, A.x);  A.y  = fmaf(wa.y, xv, A.y);
                        A.z  = fmaf(wa.z, xv, A.z);  A.w  = fmaf(wa.w, xv, A.w);
                        Bq.x = fmaf(wb.x, xv, Bq.x); Bq.y = fmaf(wb.y, xv, Bq.y);
                        Bq.z = fmaf(wb.z, xv, Bq.z); Bq.w = fmaf(wb.w, xv, Bq.w);
                        Cq.x = fmaf(wc.x, xv, Cq.x); Cq.y = fmaf(wc.y, xv, Cq.y);
                        Cq.z = fmaf(wc.z, xv, Cq.z); Cq.w = fmaf(wc.w, xv, Cq.w);
                        Dq.x = fmaf(wd.x, xv, Dq.x); Dq.y = fmaf(wd.y, xv, Dq.y);
                        Dq.z = fmaf(wd.z, xv, Dq.z); Dq.w = fmaf(wd.w, xv, Dq.w);
                    }
                }
            }
            float acc[16] = {A.x,A.y,A.z,A.w, Bq.x,Bq.y,Bq.z,Bq.w,
                             Cq.x,Cq.y,Cq.z,Cq.w, Dq.x,Dq.y,Dq.z,Dq.w};
            const bool wl = ((tid & 1) == 0) && ((tid & 16) == 0);
            const int obase = k * FSTRIDE + (oy >> 1) * 8 + (ox >> 1);
            #pragma unroll
            for (int c2 = 0; c2 < 16; ++c2) {
                float a = acc[c2];
                a = fmaxf(a, __shfl_xor(a, 1));
                a = fmaxf(a, __shfl_xor(a, 16));
                if (wl) featL[obase + c2 * 32] = fmaxf(a + b2[c2], 0.f);
            }
        }
        __syncthreads();
    }

    // ---------------- parameter transform (overlays conv scratch) ----------------
    for (int idx = tid; idx < 665; idx += TPB) {
        if (idx < 361) {
            float s = sigma[idx];
            up[idx] = make_float4(-L2E * s, L2E * s * mu[idx],
                                  ww[idx] * erev[idx], ww[idx] * mask[idx]);
        } else {
            int kk = idx - 361;
            int i = kk / 19;
            float s = ssigma[kk];
            sp[kk] = make_float4(-L2E * s * inw[i], -L2E * s * (inb[i] - smu[kk]),
                                 sw[kk] * serev[kk], sw[kk] * smask[kk]);
        }
    }
    __syncthreads();

    // ---------------- LTC: 19 lanes/image, 3 images/wave, params in VGPRs ----------------
    const int wv_ = tid >> 6, l = tid & 63;
    const int g = l / 19;                 // 0..2 active, 3 = idle tail lanes
    const int j = l - g * 19;             // 0..18 (idle lanes: 0..6, safe indices)
    const int kimg = wv_ * 3 + g;
    const bool act = (g < 3) && (b0 + kimg < BTOT);
    const int kc = (kimg < IPB) ? kimg : (IPB - 1);

    float4 UP[19], SP[16];
    #pragma unroll
    for (int i = 0; i < 19; ++i) UP[i] = up[i * 19 + j];
    #pragma unroll
    for (int i = 0; i < 16; ++i) SP[i] = sp[i * 19 + j];

    const float gl = gleak[j];
    const float gv = gl * vleak[j];
    const float cmt = cm[j] * 6.f;        // cm / (dt/unfolds), dt=1, unfolds=6

    float v = 0.f;
    if (act) vbuf[kimg * VSTRIDE + j] = 0.f;
    __builtin_amdgcn_wave_barrier();
    __asm__ volatile("" ::: "memory");

    for (int s = 0; s < SEQ; ++s) {
        const float4* fb4 = (const float4*)(featL + kc * FSTRIDE + s * 16);
        float4 f0 = fb4[0], f1 = fb4[1], f2 = fb4[2], f3 = fb4[3];
        float fv[16] = {f0.x,f0.y,f0.z,f0.w, f1.x,f1.y,f1.z,f1.w,
                        f2.x,f2.y,f2.z,f2.w, f3.x,f3.y,f3.z,f3.w};
        float wns = 0.f, wds = 0.f;
        #pragma unroll
        for (int i = 0; i < 16; ++i) {
            float t = fmaf(SP[i].x, fv[i], SP[i].y);
            float r = __builtin_amdgcn_rcpf(1.f + __builtin_amdgcn_exp2f(t));
            wns = fmaf(SP[i].z, r, wns);
            wds = fmaf(SP[i].w, r, wds);
        }
        const float nb = gv + wns;
        const float db = cmt + gl + wds;
        for (int u = 0; u < 6; ++u) {
            const float4* vb4 = (const float4*)(vbuf + kc * VSTRIDE);
            float4 va = vb4[0], vb = vb4[1], vc = vb4[2], vd = vb4[3], ve = vb4[4];
            float vv[19] = {va.x,va.y,va.z,va.w, vb.x,vb.y,vb.z,vb.w,
                            vc.x,vc.y,vc.z,vc.w, vd.x,vd.y,vd.z,vd.w,
                            ve.x,ve.y,ve.z};
            float num = fmaf(cmt, v, nb);
            float den = db;
            #pragma unroll
            for (int i = 0; i < 19; ++i) {
                float t = fmaf(UP[i].x, vv[i], UP[i].y);
                float r = __builtin_amdgcn_rcpf(1.f + __builtin_amdgcn_exp2f(t));
                num = fmaf(UP[i].z, r, num);
                den = fmaf(UP[i].w, r, den);
            }
            v = num * __builtin_amdgcn_rcpf(den + 1e-8f);
            __builtin_amdgcn_wave_barrier();
            __asm__ volatile("" ::: "memory");
            if (act) vbuf[kimg * VSTRIDE + j] = v;
            __builtin_amdgcn_wave_barrier();
            __asm__ volatile("" ::: "memory");
        }
    }
    if (act && j < 2) dout[(b0 + kimg) * 2 + j] = fmaf(v, outw[j], outb[j]);
}

extern "C" void kernel_launch(void* const* d_in, const int* in_sizes, int n_in,
                              void* d_out, int out_size, void* d_ws, size_t ws_size,
                              hipStream_t stream) {
    const float* x      = (const float*)d_in[0];
    const float* w1     = (const float*)d_in[1];
    const float* b1     = (const float*)d_in[2];
    const float* w2     = (const float*)d_in[3];
    const float* b2     = (const float*)d_in[4];
    const float* gleak  = (const float*)d_in[5];
    const float* vleak  = (const float*)d_in[6];
    const float* cm     = (const float*)d_in[7];
    const float* sigma  = (const float*)d_in[8];
    const float* mu     = (const float*)d_in[9];
    const float* ww     = (const float*)d_in[10];
    const float* erev   = (const float*)d_in[11];
    const float* ssig   = (const float*)d_in[12];
    const float* smu    = (const float*)d_in[13];
    const float* sw     = (const float*)d_in[14];
    const float* serev  = (const float*)d_in[15];
    const float* inw    = (const float*)d_in[16];
    const float* inb    = (const float*)d_in[17];
    const float* outw   = (const float*)d_in[18];
    const float* outb   = (const float*)d_in[19];
    const float* mask   = (const float*)d_in[20];
    const float* smask  = (const float*)d_in[21];
    float* wt = (float*)d_ws;   // 2400 floats

    hipLaunchKernelGGL(prep_w2t, dim3(10), dim3(256), 0, stream, w2, wt);

    dim3 grid((BTOT + IPB - 1) / IPB), block(TPB);
    hipLaunchKernelGGL(ltc_fused, grid, block, 0, stream,
                       x, w1, b1, b2, gleak, vleak, cm, sigma, mu, ww, erev,
                       ssig, smu, sw, serev, inw, inb, outw, outb, mask, smask,
                       (const float*)wt, (float*)d_out);
}

// Round 3
// 359.298 us; speedup vs baseline: 1.2635x; 1.2635x over previous
//
#include <hip/hip_runtime.h>

#define BTOT 8192
#define SEQ 32
#define IPB 6
#define TPB 128
#define L2E 1.4426950408889634f
#define FSTRIDE 520   // featL row stride in floats (kc*520 dwords: groups land on shifted banks)

__global__ __launch_bounds__(TPB, 3) void ltc_fused(
    const float* __restrict__ xin,
    const float* __restrict__ w1, const float* __restrict__ b1,
    const float* __restrict__ w2, const float* __restrict__ b2,
    const float* __restrict__ gleak, const float* __restrict__ vleak, const float* __restrict__ cm,
    const float* __restrict__ sigma, const float* __restrict__ mu, const float* __restrict__ ww,
    const float* __restrict__ erev,
    const float* __restrict__ ssigma, const float* __restrict__ smu, const float* __restrict__ sw,
    const float* __restrict__ serev,
    const float* __restrict__ inw, const float* __restrict__ inb,
    const float* __restrict__ outw, const float* __restrict__ outb,
    float* __restrict__ dout)
{
    // uni: conv scratch (img 1232 + c1p 1440 = 2672 floats),
    // later overlaid by transformed param planes (1995 floats)
    __shared__ __align__(16) float uni[2672];
    __shared__ __align__(16) float featL[IPB * FSTRIDE];

    float* img = uni;            // 28 x 44
    float* c1p = uni + 1232;     // 6 x 12 x 20
    float* uA = uni;             // 361  -L2E*sigma
    float* uB = uni + 361;       // 361   L2E*sigma*mu
    float* uZ = uni + 722;       // 361   w*erev   (|uZ| = w*mask)
    float* sA = uni + 1083;      // 304
    float* sB = uni + 1387;      // 304
    float* sZ = uni + 1691;      // 304

    const int tid = threadIdx.x;
    const int b0 = blockIdx.x * IPB;

    // ---------------- conv phase (round-1 proven code) ----------------
    for (int k = 0; k < IPB; ++k) {
        const int bG = b0 + k;
        const bool valid = bG < BTOT;
        if (valid) {
            for (int idx = tid; idx < 1232; idx += TPB) img[idx] = xin[bG * 1232 + idx];
        }
        __syncthreads();
        if (valid) {
            for (int idx = tid; idx < 1440; idx += TPB) {
                int c = idx / 240, r = idx - c * 240;
                int y = r / 20, xx = r - y * 20;
                const float* ib = img + (2 * y) * 44 + 2 * xx;
                float win[6][6];
                #pragma unroll
                for (int rr = 0; rr < 6; ++rr) {
                    float2 a = *(const float2*)(ib + rr * 44);
                    float2 b = *(const float2*)(ib + rr * 44 + 2);
                    float2 cc = *(const float2*)(ib + rr * 44 + 4);
                    win[rr][0] = a.x; win[rr][1] = a.y; win[rr][2] = b.x;
                    win[rr][3] = b.y; win[rr][4] = cc.x; win[rr][5] = cc.y;
                }
                const float* wp = w1 + c * 25;
                float a00 = 0.f, a01 = 0.f, a10 = 0.f, a11 = 0.f;
                #pragma unroll
                for (int ky = 0; ky < 5; ++ky)
                    #pragma unroll
                    for (int kx = 0; kx < 5; ++kx) {
                        float wv = wp[ky * 5 + kx];
                        a00 = fmaf(wv, win[ky][kx], a00);
                        a01 = fmaf(wv, win[ky][kx + 1], a01);
                        a10 = fmaf(wv, win[ky + 1][kx], a10);
                        a11 = fmaf(wv, win[ky + 1][kx + 1], a11);
                    }
                float m = fmaxf(fmaxf(a00, a01), fmaxf(a10, a11)) + b1[c];
                c1p[idx] = fmaxf(m, 0.f);
            }
        }
        __syncthreads();
        if (valid) {
            for (int idx = tid; idx < 512; idx += TPB) {
                int c2 = idx >> 5, r = idx & 31;
                int y = r >> 3, xx = r & 7;
                float a00 = 0.f, a01 = 0.f, a10 = 0.f, a11 = 0.f;
                for (int ch = 0; ch < 6; ++ch) {
                    const float* cb = c1p + ch * 240 + (2 * y) * 20 + 2 * xx;
                    float win[6][6];
                    #pragma unroll
                    for (int rr = 0; rr < 6; ++rr) {
                        float2 a = *(const float2*)(cb + rr * 20);
                        float2 b = *(const float2*)(cb + rr * 20 + 2);
                        float2 cc = *(const float2*)(cb + rr * 20 + 4);
                        win[rr][0] = a.x; win[rr][1] = a.y; win[rr][2] = b.x;
                        win[rr][3] = b.y; win[rr][4] = cc.x; win[rr][5] = cc.y;
                    }
                    const float* wp = w2 + (c2 * 6 + ch) * 25;
                    #pragma unroll
                    for (int ky = 0; ky < 5; ++ky)
                        #pragma unroll
                        for (int kx = 0; kx < 5; ++kx) {
                            float wv = wp[ky * 5 + kx];
                            a00 = fmaf(wv, win[ky][kx], a00);
                            a01 = fmaf(wv, win[ky][kx + 1], a01);
                            a10 = fmaf(wv, win[ky + 1][kx], a10);
                            a11 = fmaf(wv, win[ky + 1][kx + 1], a11);
                        }
                }
                float m = fmaxf(fmaxf(a00, a01), fmaxf(a10, a11)) + b2[c2];
                featL[k * FSTRIDE + idx] = fmaxf(m, 0.f);
            }
        }
        __syncthreads();
    }

    // ---------------- parameter transform (overlays conv scratch) ----------------
    for (int idx = tid; idx < 665; idx += TPB) {
        if (idx < 361) {
            float s = sigma[idx];
            uA[idx] = -L2E * s;
            uB[idx] = L2E * s * mu[idx];
            uZ[idx] = ww[idx] * erev[idx];
        } else {
            int kk = idx - 361;
            int i = kk / 19;
            float s = ssigma[kk];
            sA[kk] = -L2E * s * inw[i];
            sB[kk] = -L2E * s * (inb[i] - smu[kk]);
            sZ[kk] = sw[kk] * serev[kk];
        }
    }
    __syncthreads();

    // ---------------- LTC: 19 lanes/image, 3 images/wave, params in VGPRs,
    //                  v-exchange via shuffles (no LDS, no barriers) ----------------
    const int wv_ = tid >> 6, l = tid & 63;
    const int g = l / 19;                 // 0..2 active, 3 = idle tail lanes
    const int j = l - g * 19;             // 0..18
    const int gbase = g * 19;
    const int kimg = wv_ * 3 + g;
    const bool act = (g < 3) && (b0 + kimg < BTOT);
    const int kc = (kimg < IPB) ? kimg : (IPB - 1);

    float UA[19], UB[19], UZ[19];
    #pragma unroll
    for (int i = 0; i < 19; ++i) {
        UA[i] = uA[i * 19 + j];
        UB[i] = uB[i * 19 + j];
        UZ[i] = uZ[i * 19 + j];
    }
    float SAr[16], SBr[16], SZr[16];
    #pragma unroll
    for (int i = 0; i < 16; ++i) {
        SAr[i] = sA[i * 19 + j];
        SBr[i] = sB[i * 19 + j];
        SZr[i] = sZ[i * 19 + j];
    }

    const float gl = gleak[j];
    const float gv = gl * vleak[j];
    const float cmt = cm[j] * 6.f;        // cm / (dt/unfolds), dt=1, unfolds=6

    float v = 0.f;

    for (int s = 0; s < SEQ; ++s) {
        const float4* fb4 = (const float4*)(featL + kc * FSTRIDE + s * 16);
        float4 f0 = fb4[0], f1 = fb4[1], f2 = fb4[2], f3 = fb4[3];
        float fv[16] = {f0.x,f0.y,f0.z,f0.w, f1.x,f1.y,f1.z,f1.w,
                        f2.x,f2.y,f2.z,f2.w, f3.x,f3.y,f3.z,f3.w};
        float wns = 0.f, wds = 0.f;
        #pragma unroll
        for (int i = 0; i < 16; ++i) {
            float t = fmaf(SAr[i], fv[i], SBr[i]);
            float r = __builtin_amdgcn_rcpf(1.f + __builtin_amdgcn_exp2f(t));
            wns = fmaf(SZr[i], r, wns);
            wds = fmaf(fabsf(SZr[i]), r, wds);
        }
        const float nb = gv + wns;
        const float db = cmt + gl + wds;
        #pragma unroll 1
        for (int u = 0; u < 6; ++u) {
            float vv[19];
            #pragma unroll
            for (int i = 0; i < 19; ++i) vv[i] = __shfl(v, gbase + i);
            float num = fmaf(cmt, v, nb);
            float den = db;
            #pragma unroll
            for (int i = 0; i < 19; ++i) {
                float t = fmaf(UA[i], vv[i], UB[i]);
                float r = __builtin_amdgcn_rcpf(1.f + __builtin_amdgcn_exp2f(t));
                num = fmaf(UZ[i], r, num);
                den = fmaf(fabsf(UZ[i]), r, den);
            }
            v = num * __builtin_amdgcn_rcpf(den + 1e-8f);
        }
    }
    if (act && j < 2) dout[(b0 + kimg) * 2 + j] = fmaf(v, outw[j], outb[j]);
}

extern "C" void kernel_launch(void* const* d_in, const int* in_sizes, int n_in,
                              void* d_out, int out_size, void* d_ws, size_t ws_size,
                              hipStream_t stream) {
    const float* x      = (const float*)d_in[0];
    const float* w1     = (const float*)d_in[1];
    const float* b1     = (const float*)d_in[2];
    const float* w2     = (const float*)d_in[3];
    const float* b2     = (const float*)d_in[4];
    const float* gleak  = (const float*)d_in[5];
    const float* vleak  = (const float*)d_in[6];
    const float* cm     = (const float*)d_in[7];
    const float* sigma  = (const float*)d_in[8];
    const float* mu     = (const float*)d_in[9];
    const float* ww     = (const float*)d_in[10];
    const float* erev   = (const float*)d_in[11];
    const float* ssig   = (const float*)d_in[12];
    const float* smu    = (const float*)d_in[13];
    const float* sw     = (const float*)d_in[14];
    const float* serev  = (const float*)d_in[15];
    const float* inw    = (const float*)d_in[16];
    const float* inb    = (const float*)d_in[17];
    const float* outw   = (const float*)d_in[18];
    const float* outb   = (const float*)d_in[19];

    dim3 grid((BTOT + IPB - 1) / IPB), block(TPB);
    hipLaunchKernelGGL(ltc_fused, grid, block, 0, stream,
                       x, w1, b1, w2, b2, gleak, vleak, cm, sigma, mu, ww, erev,
                       ssig, smu, sw, serev, inw, inb, outw, outb,
                       (float*)d_out);
}

// Round 4
// 318.785 us; speedup vs baseline: 1.4241x; 1.1271x over previous
//
#include <hip/hip_runtime.h>

#define BTOT 8192
#define SEQ 32
#define IPB 6
#define TPB 128
#define L2E 1.4426950408889634f
#define FSTRIDE 520   // featL row stride (8-dword bank shift per image row)
#define VSTRIDE 20    // vbuf row stride (bank-disjoint b128 reads across 3 groups)

// transpose conv2 weights [c2][ch][ky][kx] -> wt[k*16+c2], k = ch*25+tap
__global__ void prep_w2t(const float* __restrict__ w2, float* __restrict__ wt) {
    int idx = blockIdx.x * blockDim.x + threadIdx.x;
    if (idx < 2400) {
        int k = idx >> 4, c2 = idx & 15;
        wt[idx] = w2[c2 * 150 + k];
    }
}

__global__ __launch_bounds__(TPB, 3) void ltc_fused(
    const float* __restrict__ xin,
    const float* __restrict__ w1, const float* __restrict__ b1,
    const float* __restrict__ b2,
    const float* __restrict__ gleak, const float* __restrict__ vleak, const float* __restrict__ cm,
    const float* __restrict__ sigma, const float* __restrict__ mu, const float* __restrict__ ww,
    const float* __restrict__ erev,
    const float* __restrict__ ssigma, const float* __restrict__ smu, const float* __restrict__ sw,
    const float* __restrict__ serev,
    const float* __restrict__ inw, const float* __restrict__ inb,
    const float* __restrict__ outw, const float* __restrict__ outb,
    const float* __restrict__ wt,
    float* __restrict__ dout)
{
    // uni: conv scratch (img 1232 + c1p 1440 = 2672 floats),
    // overlaid later by param planes (1995 floats)
    __shared__ __align__(16) float uni[2672];
    __shared__ __align__(16) float featL[IPB * FSTRIDE];
    __shared__ __align__(16) float vbuf[IPB * VSTRIDE];

    float* img = uni;            // 28 x 44
    float* c1p = uni + 1232;     // 6 x 12 x 20
    float* uA = uni;             // 361  -L2E*sigma
    float* uB = uni + 361;       // 361   L2E*sigma*mu
    float* uZ = uni + 722;       // 361   w*erev   (|uZ| = w*mask)
    float* sA = uni + 1083;      // 304
    float* sB = uni + 1387;      // 304
    float* sZ = uni + 1691;      // 304

    const int tid = threadIdx.x;
    const int b0 = blockIdx.x * IPB;

    // ---------------- conv phase ----------------
    for (int k = 0; k < IPB; ++k) {
        const int bG = b0 + k;
        const bool valid = bG < BTOT;
        if (valid) {
            for (int idx = tid; idx < 1232; idx += TPB) img[idx] = xin[bG * 1232 + idx];
        }
        __syncthreads();
        if (valid) {
            // conv1: thread covers pooled positions, window reused across channels
            for (int idx = tid; idx < 240; idx += TPB) {
                int y = idx / 20, xx = idx - (idx / 20) * 20;
                const float* ib = img + (2 * y) * 44 + 2 * xx;
                float win[6][6];
                #pragma unroll
                for (int r = 0; r < 6; ++r) {
                    float2 a = *(const float2*)(ib + r * 44);
                    float2 b = *(const float2*)(ib + r * 44 + 2);
                    float2 c = *(const float2*)(ib + r * 44 + 4);
                    win[r][0] = a.x; win[r][1] = a.y; win[r][2] = b.x;
                    win[r][3] = b.y; win[r][4] = c.x; win[r][5] = c.y;
                }
                for (int ch = 0; ch < 6; ++ch) {
                    const float* wp = w1 + ch * 25;   // uniform -> scalar loads
                    float a00 = 0.f, a01 = 0.f, a10 = 0.f, a11 = 0.f;
                    #pragma unroll
                    for (int ky = 0; ky < 5; ++ky)
                        #pragma unroll
                        for (int kx = 0; kx < 5; ++kx) {
                            float wv = wp[ky * 5 + kx];
                            a00 = fmaf(wv, win[ky][kx], a00);
                            a01 = fmaf(wv, win[ky][kx + 1], a01);
                            a10 = fmaf(wv, win[ky + 1][kx], a10);
                            a11 = fmaf(wv, win[ky + 1][kx + 1], a11);
                        }
                    float m = fmaxf(fmaxf(a00, a01), fmaxf(a10, a11)) + b1[ch];
                    c1p[ch * 240 + idx] = fmaxf(m, 0.f);
                }
            }
        }
        __syncthreads();
        if (valid) {
            // conv2 GEMM: thread = pre-pool position (8x16), 16 c2 accums,
            // weights via uniform loads from wt (scalar pipe), shfl_xor pooling
            const int oy = tid >> 4, ox = tid & 15;
            float acc[16];
            #pragma unroll
            for (int c2 = 0; c2 < 16; ++c2) acc[c2] = 0.f;
            for (int ch = 0; ch < 6; ++ch) {
                const float* rowb = c1p + ch * 240 + oy * 20 + ox;
                const float* wch = wt + (ch * 25 << 4);
                #pragma unroll
                for (int ky = 0; ky < 5; ++ky) {
                    #pragma unroll
                    for (int kx = 0; kx < 5; ++kx) {
                        float xv = rowb[ky * 20 + kx];
                        const float4* wk = (const float4*)(wch + ((ky * 5 + kx) << 4));
                        float4 wa = wk[0], wb = wk[1], wc = wk[2], wd = wk[3];
                        acc[0]  = fmaf(wa.x, xv, acc[0]);  acc[1]  = fmaf(wa.y, xv, acc[1]);
                        acc[2]  = fmaf(wa.z, xv, acc[2]);  acc[3]  = fmaf(wa.w, xv, acc[3]);
                        acc[4]  = fmaf(wb.x, xv, acc[4]);  acc[5]  = fmaf(wb.y, xv, acc[5]);
                        acc[6]  = fmaf(wb.z, xv, acc[6]);  acc[7]  = fmaf(wb.w, xv, acc[7]);
                        acc[8]  = fmaf(wc.x, xv, acc[8]);  acc[9]  = fmaf(wc.y, xv, acc[9]);
                        acc[10] = fmaf(wc.z, xv, acc[10]); acc[11] = fmaf(wc.w, xv, acc[11]);
                        acc[12] = fmaf(wd.x, xv, acc[12]); acc[13] = fmaf(wd.y, xv, acc[13]);
                        acc[14] = fmaf(wd.z, xv, acc[14]); acc[15] = fmaf(wd.w, xv, acc[15]);
                    }
                }
            }
            const bool wl = ((tid & 1) == 0) && ((tid & 16) == 0);
            const int obase = k * FSTRIDE + (oy >> 1) * 8 + (ox >> 1);
            #pragma unroll
            for (int c2 = 0; c2 < 16; ++c2) {
                float a = acc[c2];
                a = fmaxf(a, __shfl_xor(a, 1));
                a = fmaxf(a, __shfl_xor(a, 16));
                if (wl) featL[obase + c2 * 32] = fmaxf(a + b2[c2], 0.f);
            }
        }
        __syncthreads();
    }

    // ---------------- parameter transform (overlays conv scratch) ----------------
    for (int idx = tid; idx < 665; idx += TPB) {
        if (idx < 361) {
            float s = sigma[idx];
            uA[idx] = -L2E * s;
            uB[idx] = L2E * s * mu[idx];
            uZ[idx] = ww[idx] * erev[idx];
        } else {
            int kk = idx - 361;
            int i = kk / 19;
            float s = ssigma[kk];
            sA[kk] = -L2E * s * inw[i];
            sB[kk] = -L2E * s * (inb[i] - smu[kk]);
            sZ[kk] = sw[kk] * serev[kk];
        }
    }
    for (int idx = tid; idx < IPB * VSTRIDE; idx += TPB) vbuf[idx] = 0.f;
    __syncthreads();

    // ---------------- LTC: 19 lanes/image, 3 images/wave ----------------
    const int wv_ = tid >> 6, l = tid & 63;
    const int g = l / 19;                 // 0..2 active, 3 = idle tail
    const int j = l - g * 19;             // 0..18
    const int kimg = wv_ * 3 + g;
    const bool act = (g < 3) && (b0 + kimg < BTOT);
    const int kc = (kimg < IPB) ? kimg : (IPB - 1);

    // unfold params pinned into VGPRs (asm makes them opaque: no remat)
    float UA[19], UB[19], UZ[19];
    #pragma unroll
    for (int i = 0; i < 19; ++i) {
        UA[i] = uA[i * 19 + j];
        UB[i] = uB[i * 19 + j];
        UZ[i] = uZ[i * 19 + j];
    }
    #pragma unroll
    for (int i = 0; i < 19; ++i)
        asm volatile("" : "+v"(UA[i]), "+v"(UB[i]), "+v"(UZ[i]));

    float gl = gleak[j];
    float gv = gl * vleak[j];
    float cmt = cm[j] * 6.f;              // cm / (dt/unfolds), dt=1, unfolds=6
    asm volatile("" : "+v"(gl), "+v"(gv), "+v"(cmt));

    float v = 0.f;
    const float* sAj = sA + j;
    const float* sBj = sB + j;
    const float* sZj = sZ + j;

    for (int s = 0; s < SEQ; ++s) {
        const float4* fb4 = (const float4*)(featL + kc * FSTRIDE + s * 16);
        float4 f0 = fb4[0], f1 = fb4[1], f2 = fb4[2], f3 = fb4[3];
        float fv[16] = {f0.x,f0.y,f0.z,f0.w, f1.x,f1.y,f1.z,f1.w,
                        f2.x,f2.y,f2.z,f2.w, f3.x,f3.y,f3.z,f3.w};
        float wns = 0.f, wds = 0.f;
        #pragma unroll
        for (int i = 0; i < 16; ++i) {
            float t = fmaf(sAj[i * 19], fv[i], sBj[i * 19]);
            float r = __builtin_amdgcn_rcpf(1.f + __builtin_amdgcn_exp2f(t));
            float z = sZj[i * 19];
            wns = fmaf(z, r, wns);
            wds = fmaf(fabsf(z), r, wds);
        }
        const float nb = gv + wns;
        const float db = cmt + gl + wds;
        #pragma unroll 1
        for (int u = 0; u < 6; ++u) {
            const float4* vb4 = (const float4*)(vbuf + kc * VSTRIDE);
            float4 va = vb4[0], vb = vb4[1], vc = vb4[2], vd = vb4[3], ve = vb4[4];
            float vv[19] = {va.x,va.y,va.z,va.w, vb.x,vb.y,vb.z,vb.w,
                            vc.x,vc.y,vc.z,vc.w, vd.x,vd.y,vd.z,vd.w,
                            ve.x,ve.y,ve.z};
            float num = fmaf(cmt, v, nb);
            float den = db;
            #pragma unroll
            for (int i = 0; i < 19; ++i) {
                float t = fmaf(UA[i], vv[i], UB[i]);
                float r = __builtin_amdgcn_rcpf(1.f + __builtin_amdgcn_exp2f(t));
                num = fmaf(UZ[i], r, num);
                den = fmaf(fabsf(UZ[i]), r, den);
            }
            v = num * __builtin_amdgcn_rcpf(den + 1e-8f);
            __builtin_amdgcn_wave_barrier();
            __asm__ volatile("" ::: "memory");
            if (act) vbuf[kimg * VSTRIDE + j] = v;
            __builtin_amdgcn_wave_barrier();
            __asm__ volatile("" ::: "memory");
        }
    }
    if (act && j < 2) dout[(b0 + kimg) * 2 + j] = fmaf(v, outw[j], outb[j]);
}

extern "C" void kernel_launch(void* const* d_in, const int* in_sizes, int n_in,
                              void* d_out, int out_size, void* d_ws, size_t ws_size,
                              hipStream_t stream) {
    const float* x      = (const float*)d_in[0];
    const float* w1     = (const float*)d_in[1];
    const float* b1     = (const float*)d_in[2];
    const float* w2     = (const float*)d_in[3];
    const float* b2     = (const float*)d_in[4];
    const float* gleak  = (const float*)d_in[5];
    const float* vleak  = (const float*)d_in[6];
    const float* cm     = (const float*)d_in[7];
    const float* sigma  = (const float*)d_in[8];
    const float* mu     = (const float*)d_in[9];
    const float* ww     = (const float*)d_in[10];
    const float* erev   = (const float*)d_in[11];
    const float* ssig   = (const float*)d_in[12];
    const float* smu    = (const float*)d_in[13];
    const float* sw     = (const float*)d_in[14];
    const float* serev  = (const float*)d_in[15];
    const float* inw    = (const float*)d_in[16];
    const float* inb    = (const float*)d_in[17];
    const float* outw   = (const float*)d_in[18];
    const float* outb   = (const float*)d_in[19];
    float* wt = (float*)d_ws;   // 2400 floats

    hipLaunchKernelGGL(prep_w2t, dim3(10), dim3(256), 0, stream, w2, wt);

    dim3 grid((BTOT + IPB - 1) / IPB), block(TPB);
    hipLaunchKernelGGL(ltc_fused, grid, block, 0, stream,
                       x, w1, b1, b2, gleak, vleak, cm, sigma, mu, ww, erev,
                       ssig, smu, sw, serev, inw, inb, outw, outb,
                       (const float*)wt, (float*)d_out);
}